// Round 1
// baseline (242.155 us; speedup 1.0000x reference)
//
#include <hip/hip_runtime.h>
#include <math.h>

// ---- problem constants ----
#define NN      4096   // nodes
#define INF_    512    // in features
#define OUTF    256    // out features
#define NHEAD   4
#define HDIM    64

typedef __attribute__((ext_vector_type(8))) short  short8x;
typedef __attribute__((ext_vector_type(4))) float  float4x;

__device__ __forceinline__ unsigned short f2bf(float x) {
    union { float f; unsigned int u; } c; c.f = x;
    unsigned int r = (c.u + 0x7FFFu + ((c.u >> 16) & 1u)) >> 16;
    return (unsigned short)r;
}

__device__ __forceinline__ float lrelu(float x) { return x >= 0.f ? x : 0.2f * x; }

// ============================================================
// K1: h = feat @ W^T  (fp32), also write h^T in bf16 for K4
// grid (4 o-tiles, 64 m-tiles) x 256 thr; 64x64 tile, k-tile 32
// ============================================================
__global__ __launch_bounds__(256) void k_h_gemm(const float* __restrict__ feat,
                                                const float* __restrict__ W,
                                                float* __restrict__ h32,
                                                unsigned short* __restrict__ hT) {
    __shared__ __align__(16) float As[32 * 68];
    __shared__ __align__(16) float Ws[32 * 68];
    const int tid = threadIdx.x;
    const int o0 = blockIdx.x * 64;
    const int m0 = blockIdx.y * 64;
    const int tx = tid & 15;   // o-quad
    const int ty = tid >> 4;   // m-quad
    float acc[4][4];
    #pragma unroll
    for (int a = 0; a < 4; ++a)
        #pragma unroll
        for (int b = 0; b < 4; ++b) acc[a][b] = 0.f;

    for (int kt = 0; kt < INF_; kt += 32) {
        __syncthreads();
        #pragma unroll
        for (int e = 0; e < 8; ++e) {
            int v = tid + e * 256;
            int c = v & 31, r = v >> 5;
            As[c * 68 + r] = feat[(size_t)(m0 + r) * INF_ + kt + c];
            Ws[c * 68 + r] = W[(size_t)(o0 + r) * INF_ + kt + c];
        }
        __syncthreads();
        #pragma unroll
        for (int k = 0; k < 32; ++k) {
            float4x a4 = *(const float4x*)&As[k * 68 + ty * 4];
            float4x w4 = *(const float4x*)&Ws[k * 68 + tx * 4];
            #pragma unroll
            for (int mi = 0; mi < 4; ++mi)
                #pragma unroll
                for (int oi = 0; oi < 4; ++oi)
                    acc[mi][oi] += a4[mi] * w4[oi];
        }
    }
    // fp32 h (row-major [node][feat])
    #pragma unroll
    for (int mi = 0; mi < 4; ++mi) {
        int m = m0 + ty * 4 + mi;
        float4x v; v[0] = acc[mi][0]; v[1] = acc[mi][1]; v[2] = acc[mi][2]; v[3] = acc[mi][3];
        *(float4x*)&h32[(size_t)m * OUTF + o0 + tx * 4] = v;
    }
    // bf16 h^T ([feat][node]) — 4 consecutive m per thread pack into ushort4
    #pragma unroll
    for (int oi = 0; oi < 4; ++oi) {
        int o = o0 + tx * 4 + oi;
        ushort4 u;
        u.x = f2bf(acc[0][oi]); u.y = f2bf(acc[1][oi]);
        u.z = f2bf(acc[2][oi]); u.w = f2bf(acc[3][oi]);
        *(ushort4*)&hT[(size_t)o * NN + m0 + ty * 4] = u;
    }
}

// ============================================================
// K1b: es[n,h] = <h[n,h*64:], a[h,:64]>, ed likewise with a[h,64:]
// one block per node, wave w = head w
// ============================================================
__global__ __launch_bounds__(256) void k_edge_proj(const float* __restrict__ h32,
                                                   const float* __restrict__ a,
                                                   float* __restrict__ es,
                                                   float* __restrict__ ed) {
    const int n = blockIdx.x;
    const int w = threadIdx.x >> 6;
    const int lane = threadIdx.x & 63;
    float v  = h32[(size_t)n * OUTF + w * HDIM + lane];
    float s1 = v * a[w * 2 * HDIM + lane];
    float s2 = v * a[w * 2 * HDIM + HDIM + lane];
    #pragma unroll
    for (int off = 32; off; off >>= 1) {
        s1 += __shfl_down(s1, off);
        s2 += __shfl_down(s2, off);
    }
    if (lane == 0) { es[n * NHEAD + w] = s1; ed[n * NHEAD + w] = s2; }
}

// ============================================================
// K2: per row i: masked softmax stats + write attn_mean row (bf16)
// max trick: lrelu monotone => m_h = lrelu(es_i + max_masked ed_j)
// ============================================================
__global__ __launch_bounds__(256) void k_attn_rows(const float* __restrict__ adj,
                                                   const float* __restrict__ es,
                                                   const float* __restrict__ ed,
                                                   unsigned short* __restrict__ attn) {
    __shared__ float rbuf[16];
    const int i = blockIdx.x;
    const int tid = threadIdx.x;
    const int w = tid >> 6;
    const int lane = tid & 63;
    const float4x esv = ((const float4x*)es)[i];
    const float4x* ed4 = (const float4x*)ed;
    const float* arow = adj + (size_t)i * NN;

    // ---- P1: max of ed over masked j ----
    float mx0 = -INFINITY, mx1 = -INFINITY, mx2 = -INFINITY, mx3 = -INFINITY;
    #pragma unroll
    for (int it = 0; it < 16; ++it) {
        int j = tid + it * 256;
        if (arow[j] > 0.1f) {
            float4x e = ed4[j];
            mx0 = fmaxf(mx0, e[0]); mx1 = fmaxf(mx1, e[1]);
            mx2 = fmaxf(mx2, e[2]); mx3 = fmaxf(mx3, e[3]);
        }
    }
    #pragma unroll
    for (int off = 32; off; off >>= 1) {
        mx0 = fmaxf(mx0, __shfl_xor(mx0, off));
        mx1 = fmaxf(mx1, __shfl_xor(mx1, off));
        mx2 = fmaxf(mx2, __shfl_xor(mx2, off));
        mx3 = fmaxf(mx3, __shfl_xor(mx3, off));
    }
    if (lane == 0) {
        rbuf[w * 4 + 0] = mx0; rbuf[w * 4 + 1] = mx1;
        rbuf[w * 4 + 2] = mx2; rbuf[w * 4 + 3] = mx3;
    }
    __syncthreads();
    float mh[4];
    #pragma unroll
    for (int c = 0; c < 4; ++c) {
        float m = fmaxf(fmaxf(rbuf[c], rbuf[4 + c]), fmaxf(rbuf[8 + c], rbuf[12 + c]));
        mh[c] = lrelu(esv[c] + m);   // -inf stays -inf (row fully masked)
    }
    __syncthreads();  // protect rbuf before reuse

    // ---- P2: denom ----
    float sm0 = 0.f, sm1 = 0.f, sm2 = 0.f, sm3 = 0.f;
    #pragma unroll
    for (int it = 0; it < 16; ++it) {
        int j = tid + it * 256;
        if (arow[j] > 0.1f) {
            float4x e = ed4[j];
            sm0 += __expf(lrelu(esv[0] + e[0]) - mh[0]);
            sm1 += __expf(lrelu(esv[1] + e[1]) - mh[1]);
            sm2 += __expf(lrelu(esv[2] + e[2]) - mh[2]);
            sm3 += __expf(lrelu(esv[3] + e[3]) - mh[3]);
        }
    }
    #pragma unroll
    for (int off = 32; off; off >>= 1) {
        sm0 += __shfl_xor(sm0, off); sm1 += __shfl_xor(sm1, off);
        sm2 += __shfl_xor(sm2, off); sm3 += __shfl_xor(sm3, off);
    }
    if (lane == 0) {
        rbuf[w * 4 + 0] = sm0; rbuf[w * 4 + 1] = sm1;
        rbuf[w * 4 + 2] = sm2; rbuf[w * 4 + 3] = sm3;
    }
    __syncthreads();
    float scale[4];
    #pragma unroll
    for (int c = 0; c < 4; ++c) {
        float den = rbuf[c] + rbuf[4 + c] + rbuf[8 + c] + rbuf[12 + c];
        scale[c] = den > 0.f ? 0.25f / den : 0.f;   // fold mean over heads
    }

    // ---- P3: write attn row (bf16) ----
    #pragma unroll
    for (int it = 0; it < 16; ++it) {
        int j = tid + it * 256;
        float val = 0.f;
        if (arow[j] > 0.1f) {
            float4x e = ed4[j];
            val  = __expf(lrelu(esv[0] + e[0]) - mh[0]) * scale[0];
            val += __expf(lrelu(esv[1] + e[1]) - mh[1]) * scale[1];
            val += __expf(lrelu(esv[2] + e[2]) - mh[2]) * scale[2];
            val += __expf(lrelu(esv[3] + e[3]) - mh[3]) * scale[3];
        }
        attn[(size_t)i * NN + j] = f2bf(val);
    }
}

// ============================================================
// K4: partials[s] = attn[:, ks] @ h[ks, :]  (bf16 MFMA 16x16x32)
// grid (64 i-tiles, 4 k-splits) x 256 thr (4 waves)
// block tile 64i x 256n; wave w owns n in [w*64, w*64+64)
// ============================================================
__global__ __launch_bounds__(256) void k_out_gemm(const unsigned short* __restrict__ attn,
                                                  const unsigned short* __restrict__ hT,
                                                  float* __restrict__ partials) {
    __shared__ __align__(16) unsigned short lds_a[64 * 40];    // [i][k], stride 40 (pad 8)
    __shared__ __align__(16) unsigned short lds_h[256 * 40];   // [n][k], stride 40
    const int tid  = threadIdx.x;
    const int w    = tid >> 6;
    const int lane = tid & 63;
    const int lidx = lane & 15;
    const int quad = lane >> 4;
    const int i0    = blockIdx.x * 64;
    const int kbase = blockIdx.y * (NN / 4);

    float4x acc[4][4];
    #pragma unroll
    for (int a = 0; a < 4; ++a)
        #pragma unroll
        for (int b = 0; b < 4; ++b)
            acc[a][b] = (float4x){0.f, 0.f, 0.f, 0.f};

    for (int ks = 0; ks < 32; ++ks) {
        const int kt = kbase + ks * 32;
        __syncthreads();
        // stage attn tile [64 i][32 k]
        #pragma unroll
        for (int it = 0; it < 2; ++it) {
            int v = tid + it * 256;
            int r = v >> 3, kq = v & 7;
            *(ushort4*)&lds_a[r * 40 + kq * 4] =
                *(const ushort4*)&attn[(size_t)(i0 + r) * NN + kt + kq * 4];
        }
        // stage h^T tile [256 n][32 k]
        #pragma unroll
        for (int it = 0; it < 8; ++it) {
            int v = tid + it * 256;
            int n = v >> 3, kq = v & 7;
            *(ushort4*)&lds_h[n * 40 + kq * 4] =
                *(const ushort4*)&hT[(size_t)n * NN + kt + kq * 4];
        }
        __syncthreads();
        short8x af[4], bf[4];
        #pragma unroll
        for (int t = 0; t < 4; ++t) {
            // A[m][k]: m = lane&15 (+16*t), k = quad*8 + j
            af[t] = *(const short8x*)&lds_a[(t * 16 + lidx) * 40 + quad * 8];
            // B[k][n]: n = lane&15 (+tile offs), k = quad*8 + j  (k-contiguous in h^T)
            bf[t] = *(const short8x*)&lds_h[(w * 64 + t * 16 + lidx) * 40 + quad * 8];
        }
        #pragma unroll
        for (int it = 0; it < 4; ++it)
            #pragma unroll
            for (int nt = 0; nt < 4; ++nt)
                acc[it][nt] = __builtin_amdgcn_mfma_f32_16x16x32_bf16(
                    af[it], bf[nt], acc[it][nt], 0, 0, 0);
    }
    // epilogue: D layout col = lane&15, row = quad*4 + reg
    float* pbase = partials + (size_t)blockIdx.y * NN * OUTF;
    #pragma unroll
    for (int it = 0; it < 4; ++it)
        #pragma unroll
        for (int nt = 0; nt < 4; ++nt)
            #pragma unroll
            for (int r = 0; r < 4; ++r) {
                int row = i0 + it * 16 + quad * 4 + r;
                int col = w * 64 + nt * 16 + lidx;
                pbase[(size_t)row * OUTF + col] = acc[it][nt][r];
            }
}

// ============================================================
// K5: out = sum_s partials[s] + bias
// ============================================================
__global__ __launch_bounds__(256) void k_reduce_out(const float* __restrict__ partials,
                                                    const float* __restrict__ bias,
                                                    float* __restrict__ out) {
    const int i = blockIdx.x;
    const int n = threadIdx.x;
    float acc = bias[n];
    #pragma unroll
    for (int s = 0; s < 4; ++s)
        acc += partials[((size_t)s * NN + i) * OUTF + n];
    out[(size_t)i * OUTF + n] = acc;
}

// ============================================================
extern "C" void kernel_launch(void* const* d_in, const int* in_sizes, int n_in,
                              void* d_out, int out_size, void* d_ws, size_t ws_size,
                              hipStream_t stream) {
    const float* feat = (const float*)d_in[0];   // [4096,512]
    const float* adj  = (const float*)d_in[1];   // [4096,4096]
    const float* W    = (const float*)d_in[2];   // [256,512]
    const float* a    = (const float*)d_in[3];   // [4,128]
    const float* bias = (const float*)d_in[4];   // [256]
    float* out = (float*)d_out;                  // [4096,256] fp32

    char* ws = (char*)d_ws;
    float*          h32      = (float*)(ws + 0);                  // 4 MB
    unsigned short* hT       = (unsigned short*)(ws + 4194304);   // 2 MB  [256][4096] bf16
    float*          es       = (float*)(ws + 6291456);            // 64 KB [4096][4]
    float*          ed       = (float*)(ws + 6356992);            // 64 KB
    unsigned short* attn     = (unsigned short*)(ws + 8388608);   // 32 MB [4096][4096] bf16
    float*          partials = (float*)(ws + 41943040);           // 16 MB [4][4096][256]

    k_h_gemm   <<<dim3(4, 64),  256, 0, stream>>>(feat, W, h32, hT);
    k_edge_proj<<<NN,           256, 0, stream>>>(h32, a, es, ed);
    k_attn_rows<<<NN,           256, 0, stream>>>(adj, es, ed, attn);
    k_out_gemm <<<dim3(64, 4),  256, 0, stream>>>(attn, hT, partials);
    k_reduce_out<<<NN,          256, 0, stream>>>(partials, bias, out);
}